// Round 13
// baseline (405.082 us; speedup 1.0000x reference)
//
#include <hip/hip_runtime.h>

// SpMM: out[r,:] = in_norm[r] * sum_{e: row[e]==r} (values[e]*out_norm[col[e]]) * x[col[e],:]
// Fast path (D==256, N<=2^17): multi-split build + SW-pipelined gather.
//   binfill_ms: per-block tile (4096 edges) -> LDS histogram -> one global
//     atomic per (bin,tile) -> grouped writes (L2-resident frontier).
//   sort_bins: per-bin LDS row split, in place; row_ptr stride-129.
//   gather: bf16 x (out_norm folded); explicit 2x8 register ping-pong with
//     sched_barrier(0) so 8-16 loads stay in flight (compiler won't do it).
// Fallbacks: R10 bucket path, atomic scatter.

typedef float f32x4 __attribute__((ext_vector_type(4)));
typedef unsigned int u32x4 __attribute__((ext_vector_type(4)));
typedef unsigned long long u64;

#define BIN_LOG2   7
#define BIN_ROWS   128
#define SEG_CAP    5120
#define TILE       4096
#define MAXBINS    1024
#define OVF_CAP    8192
#define BUCKET_LOG2 6
#define BUCKET_CAP  64

// ---------------- bf16 helpers ----------------
__device__ inline unsigned pack_bf16x2(float lo, float hi) {
    unsigned ua = __float_as_uint(lo);
    unsigned ub = __float_as_uint(hi);
    ua = (ua + 0x7FFFu + ((ua >> 16) & 1u)) >> 16;        // RNE
    ub = (ub + 0x7FFFu + ((ub >> 16) & 1u)) >> 16;
    return ua | (ub << 16);
}
__device__ inline unsigned pack_bf16_1(float a) {
    unsigned u = __float_as_uint(a);
    return (u + 0x7FFFu + ((u >> 16) & 1u)) >> 16;
}
__device__ inline float bf_lo(unsigned u) { return __uint_as_float(u << 16); }
__device__ inline float bf_hi(unsigned u) { return __uint_as_float(u & 0xFFFF0000u); }

// ---------------- fallback: atomic scatter ----------------
__global__ void zero_out_kernel(float4* out, int n4) {
    int i = blockIdx.x * blockDim.x + threadIdx.x;
    int stride = gridDim.x * blockDim.x;
    for (; i < n4; i += stride) out[i] = make_float4(0.f, 0.f, 0.f, 0.f);
}

__global__ __launch_bounds__(256) void edge_scatter_kernel(
    const float* __restrict__ x, const int* __restrict__ row,
    const int* __restrict__ col, const float* __restrict__ values,
    const float* __restrict__ out_norm, const float* __restrict__ in_norm,
    float* __restrict__ out, int E, int D)
{
    int wave_in_block = threadIdx.x >> 6;
    int lane = threadIdx.x & 63;
    int e = blockIdx.x * 4 + wave_in_block;
    if (e >= E) return;
    int r = row[e], c = col[e];
    float s = values[e] * out_norm[c] * in_norm[r];
    const float4* xs = reinterpret_cast<const float4*>(x + (size_t)c * D);
    float4 v = xs[lane];
    float* o = out + (size_t)r * D + lane * 4;
    atomicAdd(o + 0, v.x * s);
    atomicAdd(o + 1, v.y * s);
    atomicAdd(o + 2, v.z * s);
    atomicAdd(o + 3, v.w * s);
}

// ---------------- x -> bf16, out_norm folded ----------------
__global__ __launch_bounds__(256) void convert_bf16_kernel(
    const u32x4* __restrict__ x, u32x4* __restrict__ xh,
    const float* __restrict__ out_norm, int n8, int d8)
{
    int i = blockIdx.x * blockDim.x + threadIdx.x;
    int stride = gridDim.x * blockDim.x;
    for (; i < n8; i += stride) {
        float s = out_norm[i / d8];
        u32x4 a = __builtin_nontemporal_load(&x[2 * i]);
        u32x4 b = __builtin_nontemporal_load(&x[2 * i + 1]);
        u32x4 o;
        o.x = pack_bf16x2(s * __uint_as_float(a.x), s * __uint_as_float(a.y));
        o.y = pack_bf16x2(s * __uint_as_float(a.z), s * __uint_as_float(a.w));
        o.z = pack_bf16x2(s * __uint_as_float(b.x), s * __uint_as_float(b.y));
        o.w = pack_bf16x2(s * __uint_as_float(b.z), s * __uint_as_float(b.w));
        xh[i] = o;
    }
}

// ---------------- multi-split bin fill ----------------
__global__ __launch_bounds__(256) void binfill_ms_kernel(
    const int* __restrict__ row, const int* __restrict__ col,
    const float* __restrict__ values,
    int* __restrict__ bin_cnt, u64* __restrict__ binbuf,
    int* __restrict__ ovf_cnt, int* __restrict__ ovf_r, u64* __restrict__ ovf_cv,
    int E, int nbins)
{
    __shared__ int hist[MAXBINS];
    __shared__ int base[MAXBINS];

    const int tid = threadIdx.x;
    const int start = blockIdx.x * TILE;

    for (int i = tid; i < nbins; i += 256) hist[i] = 0;
    __syncthreads();

    #pragma unroll
    for (int k = 0; k < TILE / 256; ++k) {
        int i = start + k * 256 + tid;
        if (i < E) {
            int r = row[i];
            atomicAdd(&hist[r >> BIN_LOG2], 1);
        }
    }
    __syncthreads();

    for (int i = tid; i < nbins; i += 256) {
        int c = hist[i];
        base[i] = c ? atomicAdd(&bin_cnt[i], c) : 0;
        hist[i] = 0;
    }
    __syncthreads();

    #pragma unroll
    for (int k = 0; k < TILE / 256; ++k) {
        int i = start + k * 256 + tid;
        if (i < E) {
            int r = row[i];
            int c = col[i];
            float v = values[i];
            int b = r >> BIN_LOG2;
            unsigned lo = (unsigned)c | ((unsigned)(r & (BIN_ROWS - 1)) << 17);
            u64 e = (u64)lo | ((u64)__float_as_uint(v) << 32);
            int rank = atomicAdd(&hist[b], 1);
            int pos = base[b] + rank;
            if (pos < SEG_CAP) {
                binbuf[(size_t)b * SEG_CAP + pos] = e;
            } else {
                int o = atomicAdd(ovf_cnt, 1);
                if (o < OVF_CAP) {
                    ovf_r[o] = (b << BIN_LOG2) + (int)((lo >> 17) & (BIN_ROWS - 1));
                    ovf_cv[o] = (u64)(lo & 0x1FFFFu) | (e & 0xFFFFFFFF00000000ull);
                }
            }
        }
    }
}

// ---------------- per-bin LDS row sort, in place ----------------
__global__ __launch_bounds__(256) void sort_bins_kernel(
    u64* __restrict__ binbuf, const int* __restrict__ bin_cnt,
    int* __restrict__ row_ptr, int nbins)
{
    __shared__ u64 sbuf[SEG_CAP];
    __shared__ int cnt[BIN_ROWS];
    __shared__ int off[BIN_ROWS];
    __shared__ int cur[BIN_ROWS];

    int b = blockIdx.x;
    int tid = threadIdx.x;
    int n = bin_cnt[b];
    if (n > SEG_CAP) n = SEG_CAP;
    const size_t seg = (size_t)b * SEG_CAP;

    for (int i = tid; i < n; i += 256) sbuf[i] = binbuf[seg + i];
    if (tid < BIN_ROWS) cnt[tid] = 0;
    __syncthreads();

    for (int i = tid; i < n; i += 256)
        atomicAdd(&cnt[(unsigned)(sbuf[i] >> 17) & (BIN_ROWS - 1)], 1);
    __syncthreads();

    if (tid < 64) {
        int lane = tid;
        int run = 0;
        for (int base = 0; base < BIN_ROWS; base += 64) {
            int v = cnt[base + lane];
            int s = v;
            #pragma unroll
            for (int d = 1; d < 64; d <<= 1) {
                int t = __shfl_up(s, d);
                if (lane >= d) s += t;
            }
            off[base + lane] = run + s - v;
            run += __shfl(s, 63);
        }
    }
    __syncthreads();
    if (tid < BIN_ROWS) {
        cur[tid] = off[tid];
        row_ptr[b * (BIN_ROWS + 1) + tid] = (int)seg + off[tid];
    }
    if (tid == 0) row_ptr[b * (BIN_ROWS + 1) + BIN_ROWS] = (int)seg + n;
    __syncthreads();

    for (int i = tid; i < n; i += 256) {
        u64 e = sbuf[i];
        int rl = (unsigned)(e >> 17) & (BIN_ROWS - 1);
        int p = atomicAdd(&cur[rl], 1);
        binbuf[seg + p] = e;
    }
}

// ---------------- gather: SW-pipelined 2x8 register ping-pong ----------------
#define GLOAD8(Q, V, KK)                                                        \
    _Pragma("unroll")                                                           \
    for (int t = 0; t < 8; ++t) {                                               \
        unsigned lo = (unsigned)__builtin_amdgcn_readlane((int)prlo, (KK) + t); \
        unsigned vbits = (unsigned)__builtin_amdgcn_readlane((int)prhi, (KK) + t); \
        V[t] = __uint_as_float(vbits);                                          \
        Q[t] = xr[(size_t)(lo & 0x1FFFFu) * DU2 + lane];                        \
    }

#define GFMA8(Q, V)                                                             \
    _Pragma("unroll")                                                           \
    for (int t = 0; t < 8; ++t) {                                               \
        acc.x += V[t] * bf_lo(Q[t].x);                                          \
        acc.y += V[t] * bf_hi(Q[t].x);                                          \
        acc.z += V[t] * bf_lo(Q[t].y);                                          \
        acc.w += V[t] * bf_hi(Q[t].y);                                          \
    }

__global__ __launch_bounds__(256) void gather_csr_kernel(
    const unsigned short* __restrict__ xh, const u64* __restrict__ binbuf,
    const int* __restrict__ row_ptr, const float* __restrict__ in_norm,
    float* __restrict__ out, int N)
{
    const int DU2 = 64;                       // uint2 (4 bf16) per row, D=256
    int wid = threadIdx.x >> 6;
    int lane = threadIdx.x & 63;
    int r = blockIdx.x * 4 + wid;
    if (r >= N) return;

    int idx = (r >> BIN_LOG2) * (BIN_ROWS + 1) + (r & (BIN_ROWS - 1));
    int beg = row_ptr[idx], end = row_ptr[idx + 1];

    float4 acc = make_float4(0.f, 0.f, 0.f, 0.f);
    const uint2* xr = reinterpret_cast<const uint2*>(xh);

    for (int base = beg; base < end; base += 64) {
        int j = base + lane;
        u64 pr = (j < end) ? __builtin_nontemporal_load(&binbuf[j]) : 0ull;
        unsigned prlo = (unsigned)(pr & 0xFFFFFFFFu);
        unsigned prhi = (unsigned)(pr >> 32);
        int m = min(64, end - base);
        int nb8 = (m + 7) >> 3;               // 8-batches, zero-padded (pr=0 pads)

        uint2 qa[8]; float va[8];
        uint2 qb[8]; float vb[8];

        // prologue: batch 0 -> A
        GLOAD8(qa, va, 0)
        __builtin_amdgcn_sched_barrier(0);

        bool curA = true;                      // A holds oldest unconsumed batch
        for (int tb = 1; tb < nb8; ++tb) {
            int kk = tb * 8;
            if (curA) {
                GLOAD8(qb, vb, kk)             // issue 8 loads (in flight)
                __builtin_amdgcn_sched_barrier(0);
                GFMA8(qa, va)                  // consume previous batch
                __builtin_amdgcn_sched_barrier(0);
            } else {
                GLOAD8(qa, va, kk)
                __builtin_amdgcn_sched_barrier(0);
                GFMA8(qb, vb)
                __builtin_amdgcn_sched_barrier(0);
            }
            curA = !curA;
        }
        if (curA) { GFMA8(qa, va) } else { GFMA8(qb, vb) }
    }

    float sc = in_norm[r];
    f32x4 o;
    o.x = acc.x * sc; o.y = acc.y * sc; o.z = acc.z * sc; o.w = acc.w * sc;
    f32x4* ob = reinterpret_cast<f32x4*>(out);
    __builtin_nontemporal_store(o, &ob[(size_t)r * DU2 + lane]);
}

// ---------------- overflow fixup (normally 0 entries) ----------------
__global__ __launch_bounds__(256) void fixup_kernel(
    const unsigned short* __restrict__ xh, const int* __restrict__ ovf_cnt,
    const int* __restrict__ ovf_r, const u64* __restrict__ ovf_cv,
    const float* __restrict__ in_norm, float* __restrict__ out)
{
    const int DU2 = 64;
    int total = *ovf_cnt;
    if (total > OVF_CAP) total = OVF_CAP;
    int wid = (blockIdx.x * blockDim.x + threadIdx.x) >> 6;
    int nw = (gridDim.x * blockDim.x) >> 6;
    int lane = threadIdx.x & 63;
    const uint2* xr = reinterpret_cast<const uint2*>(xh);
    for (int i = wid; i < total; i += nw) {
        int r = ovf_r[i];
        u64 p = ovf_cv[i];
        int c = (int)(unsigned)(p & 0xFFFFFFFFu);
        float v = __uint_as_float((unsigned)(p >> 32)) * in_norm[r];
        uint2 q = xr[(size_t)(unsigned)c * DU2 + lane];
        float* o = out + (size_t)r * 256 + lane * 4;
        atomicAdd(o + 0, v * bf_lo(q.x));
        atomicAdd(o + 1, v * bf_hi(q.x));
        atomicAdd(o + 2, v * bf_lo(q.y));
        atomicAdd(o + 3, v * bf_hi(q.y));
    }
}

// ================= R10 bucket path (fallback, D==256) =================
__global__ __launch_bounds__(256) void fill_bucket4_kernel(
    const int* __restrict__ row, const int* __restrict__ col,
    const float* __restrict__ values,
    int* __restrict__ cursor, unsigned* __restrict__ pairs,
    int* __restrict__ ovf_cnt, int* __restrict__ ovf_r, u64* __restrict__ ovf_cv,
    int E)
{
    int i = blockIdx.x * blockDim.x + threadIdx.x;
    int stride = gridDim.x * blockDim.x;
    for (; i < E; i += stride) {
        int r = __builtin_nontemporal_load(&row[i]);
        int c = __builtin_nontemporal_load(&col[i]);
        float v = __builtin_nontemporal_load(&values[i]);
        int n = atomicAdd(&cursor[r], 1);
        if (n < BUCKET_CAP) {
            unsigned entry = ((unsigned)c << 15) | (pack_bf16_1(v) & 0x7FFFu);
            pairs[((size_t)r << BUCKET_LOG2) + n] = entry;
        } else {
            int o = atomicAdd(ovf_cnt, 1);
            if (o < OVF_CAP) {
                ovf_r[o] = r;
                ovf_cv[o] = (u64)(unsigned)c | ((u64)__float_as_uint(v) << 32);
            }
        }
    }
}

__global__ __launch_bounds__(256) void gather_bucket4_kernel(
    const unsigned short* __restrict__ xh, const unsigned* __restrict__ pairs,
    const int* __restrict__ cursor, const float* __restrict__ in_norm,
    float* __restrict__ out, int N)
{
    const int DU2 = 64;
    int wid = threadIdx.x >> 6;
    int lane = threadIdx.x & 63;
    int r = blockIdx.x * 4 + wid;
    if (r >= N) return;

    int m = cursor[r];
    if (m > BUCKET_CAP) m = BUCKET_CAP;

    unsigned pr = (lane < m)
        ? __builtin_nontemporal_load(&pairs[((size_t)r << BUCKET_LOG2) + lane])
        : 0u;

    float4 acc = make_float4(0.f, 0.f, 0.f, 0.f);
    const uint2* xr = reinterpret_cast<const uint2*>(xh);

    for (int kk = 0; kk < m; kk += 16) {
        uint2 q[16]; float vv[16];
        #pragma unroll
        for (int t = 0; t < 16; ++t) {
            unsigned p = (unsigned)__builtin_amdgcn_readlane((int)pr, kk + t);
            vv[t] = __uint_as_float((p & 0x7FFFu) << 16);
            unsigned c = p >> 15;
            q[t] = xr[(size_t)c * DU2 + lane];
        }
        #pragma unroll
        for (int t = 0; t < 16; ++t) {
            acc.x += vv[t] * bf_lo(q[t].x);
            acc.y += vv[t] * bf_hi(q[t].x);
            acc.z += vv[t] * bf_lo(q[t].y);
            acc.w += vv[t] * bf_hi(q[t].y);
        }
    }

    float sc = in_norm[r];
    f32x4 o;
    o.x = acc.x * sc; o.y = acc.y * sc; o.z = acc.z * sc; o.w = acc.w * sc;
    f32x4* ob = reinterpret_cast<f32x4*>(out);
    __builtin_nontemporal_store(o, &ob[(size_t)r * DU2 + lane]);
}

extern "C" void kernel_launch(void* const* d_in, const int* in_sizes, int n_in,
                              void* d_out, int out_size, void* d_ws, size_t ws_size,
                              hipStream_t stream) {
    const float* x        = (const float*)d_in[0];
    const int*   row      = (const int*)  d_in[1];
    const int*   col      = (const int*)  d_in[2];
    const float* values   = (const float*)d_in[3];
    const float* out_norm = (const float*)d_in[4];
    const float* in_norm  = (const float*)d_in[5];
    float* out = (float*)d_out;

    const int E = in_sizes[1];
    const int N = in_sizes[4];
    const int D = in_sizes[0] / N;   // 256

    // ---------- fast path: multi-split binning (D==256, N<=2^17) ----------
    {
        const int nbins = (N + BIN_ROWS - 1) >> BIN_LOG2;
        const int nrp = nbins * (BIN_ROWS + 1);
        size_t off = 0;
        size_t cnt_off  = off;                off += (size_t)nbins * 4;
        size_t ovfc_off = off;                off += 16;
        size_t ovfr_off = off;                off += (size_t)OVF_CAP * 4;
        off = (off + 15) & ~(size_t)15;
        size_t ovfcv_off = off;               off += (size_t)OVF_CAP * 8;
        size_t rptr_off  = off;               off += (size_t)nrp * 4;
        off = (off + 15) & ~(size_t)15;
        size_t binbuf_off = off;              off += (size_t)nbins * SEG_CAP * 8;
        off = (off + 15) & ~(size_t)15;
        size_t xh_off    = off;               off += (size_t)N * D * 2;
        size_t need = off;

        if (D == 256 && N <= (1 << 17) && nbins <= MAXBINS && ws_size >= need) {
            int* bin_cnt = (int*)((char*)d_ws + cnt_off);
            int* ovf_cnt = (int*)((char*)d_ws + ovfc_off);
            int* ovf_r   = (int*)((char*)d_ws + ovfr_off);
            u64* ovf_cv  = (u64*)((char*)d_ws + ovfcv_off);
            int* row_ptr = (int*)((char*)d_ws + rptr_off);
            u64* binbuf  = (u64*)((char*)d_ws + binbuf_off);
            unsigned short* xh = (unsigned short*)((char*)d_ws + xh_off);

            (void)hipMemsetAsync(bin_cnt, 0, (size_t)nbins * 4 + 16, stream);
            int n8 = (N * D) / 8;
            convert_bf16_kernel<<<2048, 256, 0, stream>>>(
                (const u32x4*)x, (u32x4*)xh, out_norm, n8, D / 8);
            int ntiles = (E + TILE - 1) / TILE;
            binfill_ms_kernel<<<ntiles, 256, 0, stream>>>(
                row, col, values, bin_cnt, binbuf, ovf_cnt, ovf_r, ovf_cv,
                E, nbins);
            sort_bins_kernel<<<nbins, 256, 0, stream>>>(
                binbuf, bin_cnt, row_ptr, nbins);
            gather_csr_kernel<<<(N + 3) / 4, 256, 0, stream>>>(
                xh, binbuf, row_ptr, in_norm, out, N);
            fixup_kernel<<<8, 256, 0, stream>>>(
                xh, ovf_cnt, ovf_r, ovf_cv, in_norm, out);
            return;
        }
    }

    // ---------- R10 bucket fallback (D==256) ----------
    {
        size_t off = 0;
        size_t cursor_off = off;              off += (size_t)N * 4;
        size_t ovfc_off   = off;              off += 16;
        size_t ovfr_off   = off;              off += (size_t)OVF_CAP * 4;
        off = (off + 15) & ~(size_t)15;
        size_t ovfcv_off  = off;              off += (size_t)OVF_CAP * 8;
        off = (off + 15) & ~(size_t)15;
        size_t pairs_off  = off;              off += ((size_t)N << BUCKET_LOG2) * 4;
        off = (off + 15) & ~(size_t)15;
        size_t xh_off     = off;              off += (size_t)N * D * 2;
        size_t need_bucket = off;

        if (D == 256 && N <= (1 << 17) && ws_size >= need_bucket) {
            int*      cursor  = (int*)((char*)d_ws + cursor_off);
            int*      ovf_cnt = (int*)((char*)d_ws + ovfc_off);
            int*      ovf_r   = (int*)((char*)d_ws + ovfr_off);
            u64*      ovf_cv  = (u64*)((char*)d_ws + ovfcv_off);
            unsigned* pairs   = (unsigned*)((char*)d_ws + pairs_off);
            unsigned short* xh = (unsigned short*)((char*)d_ws + xh_off);

            (void)hipMemsetAsync(cursor, 0, (size_t)N * 4 + 16, stream);
            int n8 = (N * D) / 8;
            convert_bf16_kernel<<<2048, 256, 0, stream>>>(
                (const u32x4*)x, (u32x4*)xh, out_norm, n8, D / 8);
            fill_bucket4_kernel<<<2048, 256, 0, stream>>>(
                row, col, values, cursor, pairs, ovf_cnt, ovf_r, ovf_cv, E);
            gather_bucket4_kernel<<<(N + 3) / 4, 256, 0, stream>>>(
                xh, pairs, cursor, in_norm, out, N);
            fixup_kernel<<<8, 256, 0, stream>>>(
                xh, ovf_cnt, ovf_r, ovf_cv, in_norm, out);
            return;
        }
    }

    // ---------- last resort: atomic scatter ----------
    int n4 = (N * D) / 4;
    zero_out_kernel<<<2048, 256, 0, stream>>>((float4*)out, n4);
    int blocks = (E + 3) / 4;
    edge_scatter_kernel<<<blocks, 256, 0, stream>>>(
        x, row, col, values, out_norm, in_norm, out, E, D);
}

// Round 14
// 400.453 us; speedup vs baseline: 1.0116x; 1.0116x over previous
//
#include <hip/hip_runtime.h>

// SpMM: out[r,:] = in_norm[r] * sum_{e: row[e]==r} (values[e]*out_norm[col[e]]) * x[col[e],:]
// Fast path (D==256, N<=2^17): multi-split build + batched register gather.
//   binfill_ms: per-block tile (4096 edges) -> LDS histogram -> one global
//     atomic per (bin,tile) -> grouped writes (L2-resident frontier).
//   sort_bins: per-bin LDS row split, in place; row_ptr stride-129.
//   gather: bf16 x (out_norm folded), 16-deep batched MLP (R12 form —
//     ping-pong/deeper ILP all measured neutral; gather is memory-bound
//     at ~6.5 TB/s effective).
// Fallbacks: R10 bucket path, atomic scatter.

typedef float f32x4 __attribute__((ext_vector_type(4)));
typedef unsigned int u32x4 __attribute__((ext_vector_type(4)));
typedef unsigned long long u64;

#define BIN_LOG2   7
#define BIN_ROWS   128
#define SEG_CAP    5120
#define TILE       4096
#define MAXBINS    1024
#define OVF_CAP    8192
#define BUCKET_LOG2 6
#define BUCKET_CAP  64

// ---------------- bf16 helpers ----------------
__device__ inline unsigned pack_bf16x2(float lo, float hi) {
    unsigned ua = __float_as_uint(lo);
    unsigned ub = __float_as_uint(hi);
    ua = (ua + 0x7FFFu + ((ua >> 16) & 1u)) >> 16;        // RNE
    ub = (ub + 0x7FFFu + ((ub >> 16) & 1u)) >> 16;
    return ua | (ub << 16);
}
__device__ inline unsigned pack_bf16_1(float a) {
    unsigned u = __float_as_uint(a);
    return (u + 0x7FFFu + ((u >> 16) & 1u)) >> 16;
}
__device__ inline float bf_lo(unsigned u) { return __uint_as_float(u << 16); }
__device__ inline float bf_hi(unsigned u) { return __uint_as_float(u & 0xFFFF0000u); }

// ---------------- fallback: atomic scatter ----------------
__global__ void zero_out_kernel(float4* out, int n4) {
    int i = blockIdx.x * blockDim.x + threadIdx.x;
    int stride = gridDim.x * blockDim.x;
    for (; i < n4; i += stride) out[i] = make_float4(0.f, 0.f, 0.f, 0.f);
}

__global__ __launch_bounds__(256) void edge_scatter_kernel(
    const float* __restrict__ x, const int* __restrict__ row,
    const int* __restrict__ col, const float* __restrict__ values,
    const float* __restrict__ out_norm, const float* __restrict__ in_norm,
    float* __restrict__ out, int E, int D)
{
    int wave_in_block = threadIdx.x >> 6;
    int lane = threadIdx.x & 63;
    int e = blockIdx.x * 4 + wave_in_block;
    if (e >= E) return;
    int r = row[e], c = col[e];
    float s = values[e] * out_norm[c] * in_norm[r];
    const float4* xs = reinterpret_cast<const float4*>(x + (size_t)c * D);
    float4 v = xs[lane];
    float* o = out + (size_t)r * D + lane * 4;
    atomicAdd(o + 0, v.x * s);
    atomicAdd(o + 1, v.y * s);
    atomicAdd(o + 2, v.z * s);
    atomicAdd(o + 3, v.w * s);
}

// ---------------- x -> bf16, out_norm folded (D==256: shift not divide) -----
__global__ __launch_bounds__(256) void convert_bf16_256_kernel(
    const u32x4* __restrict__ x, u32x4* __restrict__ xh,
    const float* __restrict__ out_norm, int n8)
{
    int i = blockIdx.x * blockDim.x + threadIdx.x;
    int stride = gridDim.x * blockDim.x;
    for (; i < n8; i += stride) {
        float s = out_norm[i >> 5];           // D==256 -> 32 groups of 8 per row
        u32x4 a = __builtin_nontemporal_load(&x[2 * i]);
        u32x4 b = __builtin_nontemporal_load(&x[2 * i + 1]);
        u32x4 o;
        o.x = pack_bf16x2(s * __uint_as_float(a.x), s * __uint_as_float(a.y));
        o.y = pack_bf16x2(s * __uint_as_float(a.z), s * __uint_as_float(a.w));
        o.z = pack_bf16x2(s * __uint_as_float(b.x), s * __uint_as_float(b.y));
        o.w = pack_bf16x2(s * __uint_as_float(b.z), s * __uint_as_float(b.w));
        xh[i] = o;
    }
}

// generic-D variant (fallback path)
__global__ __launch_bounds__(256) void convert_bf16_kernel(
    const u32x4* __restrict__ x, u32x4* __restrict__ xh,
    const float* __restrict__ out_norm, int n8, int d8)
{
    int i = blockIdx.x * blockDim.x + threadIdx.x;
    int stride = gridDim.x * blockDim.x;
    for (; i < n8; i += stride) {
        float s = out_norm[i / d8];
        u32x4 a = __builtin_nontemporal_load(&x[2 * i]);
        u32x4 b = __builtin_nontemporal_load(&x[2 * i + 1]);
        u32x4 o;
        o.x = pack_bf16x2(s * __uint_as_float(a.x), s * __uint_as_float(a.y));
        o.y = pack_bf16x2(s * __uint_as_float(a.z), s * __uint_as_float(a.w));
        o.z = pack_bf16x2(s * __uint_as_float(b.x), s * __uint_as_float(b.y));
        o.w = pack_bf16x2(s * __uint_as_float(b.z), s * __uint_as_float(b.w));
        xh[i] = o;
    }
}

// ---------------- multi-split bin fill ----------------
__global__ __launch_bounds__(256) void binfill_ms_kernel(
    const int* __restrict__ row, const int* __restrict__ col,
    const float* __restrict__ values,
    int* __restrict__ bin_cnt, u64* __restrict__ binbuf,
    int* __restrict__ ovf_cnt, int* __restrict__ ovf_r, u64* __restrict__ ovf_cv,
    int E, int nbins)
{
    __shared__ int hist[MAXBINS];
    __shared__ int base[MAXBINS];

    const int tid = threadIdx.x;
    const int start = blockIdx.x * TILE;

    for (int i = tid; i < nbins; i += 256) hist[i] = 0;
    __syncthreads();

    #pragma unroll
    for (int k = 0; k < TILE / 256; ++k) {
        int i = start + k * 256 + tid;
        if (i < E) {
            int r = row[i];
            atomicAdd(&hist[r >> BIN_LOG2], 1);
        }
    }
    __syncthreads();

    for (int i = tid; i < nbins; i += 256) {
        int c = hist[i];
        base[i] = c ? atomicAdd(&bin_cnt[i], c) : 0;
        hist[i] = 0;
    }
    __syncthreads();

    #pragma unroll
    for (int k = 0; k < TILE / 256; ++k) {
        int i = start + k * 256 + tid;
        if (i < E) {
            int r = row[i];
            int c = col[i];
            float v = values[i];
            int b = r >> BIN_LOG2;
            unsigned lo = (unsigned)c | ((unsigned)(r & (BIN_ROWS - 1)) << 17);
            u64 e = (u64)lo | ((u64)__float_as_uint(v) << 32);
            int rank = atomicAdd(&hist[b], 1);
            int pos = base[b] + rank;
            if (pos < SEG_CAP) {
                binbuf[(size_t)b * SEG_CAP + pos] = e;
            } else {
                int o = atomicAdd(ovf_cnt, 1);
                if (o < OVF_CAP) {
                    ovf_r[o] = (b << BIN_LOG2) + (int)((lo >> 17) & (BIN_ROWS - 1));
                    ovf_cv[o] = (u64)(lo & 0x1FFFFu) | (e & 0xFFFFFFFF00000000ull);
                }
            }
        }
    }
}

// ---------------- per-bin LDS row sort, in place ----------------
__global__ __launch_bounds__(256) void sort_bins_kernel(
    u64* __restrict__ binbuf, const int* __restrict__ bin_cnt,
    int* __restrict__ row_ptr, int nbins)
{
    __shared__ u64 sbuf[SEG_CAP];
    __shared__ int cnt[BIN_ROWS];
    __shared__ int off[BIN_ROWS];
    __shared__ int cur[BIN_ROWS];

    int b = blockIdx.x;
    int tid = threadIdx.x;
    int n = bin_cnt[b];
    if (n > SEG_CAP) n = SEG_CAP;
    const size_t seg = (size_t)b * SEG_CAP;

    for (int i = tid; i < n; i += 256) sbuf[i] = binbuf[seg + i];
    if (tid < BIN_ROWS) cnt[tid] = 0;
    __syncthreads();

    for (int i = tid; i < n; i += 256)
        atomicAdd(&cnt[(unsigned)(sbuf[i] >> 17) & (BIN_ROWS - 1)], 1);
    __syncthreads();

    if (tid < 64) {
        int lane = tid;
        int run = 0;
        for (int base = 0; base < BIN_ROWS; base += 64) {
            int v = cnt[base + lane];
            int s = v;
            #pragma unroll
            for (int d = 1; d < 64; d <<= 1) {
                int t = __shfl_up(s, d);
                if (lane >= d) s += t;
            }
            off[base + lane] = run + s - v;
            run += __shfl(s, 63);
        }
    }
    __syncthreads();
    if (tid < BIN_ROWS) {
        cur[tid] = off[tid];
        row_ptr[b * (BIN_ROWS + 1) + tid] = (int)seg + off[tid];
    }
    if (tid == 0) row_ptr[b * (BIN_ROWS + 1) + BIN_ROWS] = (int)seg + n;
    __syncthreads();

    for (int i = tid; i < n; i += 256) {
        u64 e = sbuf[i];
        int rl = (unsigned)(e >> 17) & (BIN_ROWS - 1);
        int p = atomicAdd(&cur[rl], 1);
        binbuf[seg + p] = e;
    }
}

// ---------------- gather: R12 form (16-deep batched, zero-padded) -----------
__global__ __launch_bounds__(256) void gather_csr_kernel(
    const unsigned short* __restrict__ xh, const u64* __restrict__ binbuf,
    const int* __restrict__ row_ptr, const float* __restrict__ in_norm,
    float* __restrict__ out, int N)
{
    const int DU2 = 64;                       // uint2 (4 bf16) per row, D=256
    int wid = threadIdx.x >> 6;
    int lane = threadIdx.x & 63;
    int r = blockIdx.x * 4 + wid;
    if (r >= N) return;

    int idx = (r >> BIN_LOG2) * (BIN_ROWS + 1) + (r & (BIN_ROWS - 1));
    int beg = row_ptr[idx], end = row_ptr[idx + 1];

    float4 acc = make_float4(0.f, 0.f, 0.f, 0.f);
    const uint2* xr = reinterpret_cast<const uint2*>(xh);

    for (int base = beg; base < end; base += 64) {
        int j = base + lane;
        u64 pr = (j < end) ? __builtin_nontemporal_load(&binbuf[j]) : 0ull;
        unsigned prlo = (unsigned)(pr & 0xFFFFFFFFu);
        unsigned prhi = (unsigned)(pr >> 32);
        int m = min(64, end - base);
        for (int kk = 0; kk < m; kk += 16) {
            uint2 q[16]; float vv[16];
            #pragma unroll
            for (int t = 0; t < 16; ++t) {
                unsigned lo = (unsigned)__builtin_amdgcn_readlane((int)prlo, kk + t);
                unsigned vb = (unsigned)__builtin_amdgcn_readlane((int)prhi, kk + t);
                vv[t] = __uint_as_float(vb);
                unsigned c = lo & 0x1FFFFu;
                q[t] = xr[(size_t)c * DU2 + lane];   // 16 independent loads
            }
            #pragma unroll
            for (int t = 0; t < 16; ++t) {
                acc.x += vv[t] * bf_lo(q[t].x);
                acc.y += vv[t] * bf_hi(q[t].x);
                acc.z += vv[t] * bf_lo(q[t].y);
                acc.w += vv[t] * bf_hi(q[t].y);
            }
        }
    }

    float sc = in_norm[r];
    f32x4 o;
    o.x = acc.x * sc; o.y = acc.y * sc; o.z = acc.z * sc; o.w = acc.w * sc;
    f32x4* ob = reinterpret_cast<f32x4*>(out);
    __builtin_nontemporal_store(o, &ob[(size_t)r * DU2 + lane]);
}

// ---------------- overflow fixup (normally 0 entries) ----------------
__global__ __launch_bounds__(256) void fixup_kernel(
    const unsigned short* __restrict__ xh, const int* __restrict__ ovf_cnt,
    const int* __restrict__ ovf_r, const u64* __restrict__ ovf_cv,
    const float* __restrict__ in_norm, float* __restrict__ out)
{
    const int DU2 = 64;
    int total = *ovf_cnt;
    if (total > OVF_CAP) total = OVF_CAP;
    int wid = (blockIdx.x * blockDim.x + threadIdx.x) >> 6;
    int nw = (gridDim.x * blockDim.x) >> 6;
    int lane = threadIdx.x & 63;
    const uint2* xr = reinterpret_cast<const uint2*>(xh);
    for (int i = wid; i < total; i += nw) {
        int r = ovf_r[i];
        u64 p = ovf_cv[i];
        int c = (int)(unsigned)(p & 0xFFFFFFFFu);
        float v = __uint_as_float((unsigned)(p >> 32)) * in_norm[r];
        uint2 q = xr[(size_t)(unsigned)c * DU2 + lane];
        float* o = out + (size_t)r * 256 + lane * 4;
        atomicAdd(o + 0, v * bf_lo(q.x));
        atomicAdd(o + 1, v * bf_hi(q.x));
        atomicAdd(o + 2, v * bf_lo(q.y));
        atomicAdd(o + 3, v * bf_hi(q.y));
    }
}

// ================= R10 bucket path (fallback, D==256) =================
__global__ __launch_bounds__(256) void fill_bucket4_kernel(
    const int* __restrict__ row, const int* __restrict__ col,
    const float* __restrict__ values,
    int* __restrict__ cursor, unsigned* __restrict__ pairs,
    int* __restrict__ ovf_cnt, int* __restrict__ ovf_r, u64* __restrict__ ovf_cv,
    int E)
{
    int i = blockIdx.x * blockDim.x + threadIdx.x;
    int stride = gridDim.x * blockDim.x;
    for (; i < E; i += stride) {
        int r = __builtin_nontemporal_load(&row[i]);
        int c = __builtin_nontemporal_load(&col[i]);
        float v = __builtin_nontemporal_load(&values[i]);
        int n = atomicAdd(&cursor[r], 1);
        if (n < BUCKET_CAP) {
            unsigned entry = ((unsigned)c << 15) | (pack_bf16_1(v) & 0x7FFFu);
            pairs[((size_t)r << BUCKET_LOG2) + n] = entry;
        } else {
            int o = atomicAdd(ovf_cnt, 1);
            if (o < OVF_CAP) {
                ovf_r[o] = r;
                ovf_cv[o] = (u64)(unsigned)c | ((u64)__float_as_uint(v) << 32);
            }
        }
    }
}

__global__ __launch_bounds__(256) void gather_bucket4_kernel(
    const unsigned short* __restrict__ xh, const unsigned* __restrict__ pairs,
    const int* __restrict__ cursor, const float* __restrict__ in_norm,
    float* __restrict__ out, int N)
{
    const int DU2 = 64;
    int wid = threadIdx.x >> 6;
    int lane = threadIdx.x & 63;
    int r = blockIdx.x * 4 + wid;
    if (r >= N) return;

    int m = cursor[r];
    if (m > BUCKET_CAP) m = BUCKET_CAP;

    unsigned pr = (lane < m)
        ? __builtin_nontemporal_load(&pairs[((size_t)r << BUCKET_LOG2) + lane])
        : 0u;

    float4 acc = make_float4(0.f, 0.f, 0.f, 0.f);
    const uint2* xr = reinterpret_cast<const uint2*>(xh);

    for (int kk = 0; kk < m; kk += 16) {
        uint2 q[16]; float vv[16];
        #pragma unroll
        for (int t = 0; t < 16; ++t) {
            unsigned p = (unsigned)__builtin_amdgcn_readlane((int)pr, kk + t);
            vv[t] = __uint_as_float((p & 0x7FFFu) << 16);
            unsigned c = p >> 15;
            q[t] = xr[(size_t)c * DU2 + lane];
        }
        #pragma unroll
        for (int t = 0; t < 16; ++t) {
            acc.x += vv[t] * bf_lo(q[t].x);
            acc.y += vv[t] * bf_hi(q[t].x);
            acc.z += vv[t] * bf_lo(q[t].y);
            acc.w += vv[t] * bf_hi(q[t].y);
        }
    }

    float sc = in_norm[r];
    f32x4 o;
    o.x = acc.x * sc; o.y = acc.y * sc; o.z = acc.z * sc; o.w = acc.w * sc;
    f32x4* ob = reinterpret_cast<f32x4*>(out);
    __builtin_nontemporal_store(o, &ob[(size_t)r * DU2 + lane]);
}

extern "C" void kernel_launch(void* const* d_in, const int* in_sizes, int n_in,
                              void* d_out, int out_size, void* d_ws, size_t ws_size,
                              hipStream_t stream) {
    const float* x        = (const float*)d_in[0];
    const int*   row      = (const int*)  d_in[1];
    const int*   col      = (const int*)  d_in[2];
    const float* values   = (const float*)d_in[3];
    const float* out_norm = (const float*)d_in[4];
    const float* in_norm  = (const float*)d_in[5];
    float* out = (float*)d_out;

    const int E = in_sizes[1];
    const int N = in_sizes[4];
    const int D = in_sizes[0] / N;   // 256

    // ---------- fast path: multi-split binning (D==256, N<=2^17) ----------
    {
        const int nbins = (N + BIN_ROWS - 1) >> BIN_LOG2;
        const int nrp = nbins * (BIN_ROWS + 1);
        size_t off = 0;
        size_t cnt_off  = off;                off += (size_t)nbins * 4;
        size_t ovfc_off = off;                off += 16;
        size_t ovfr_off = off;                off += (size_t)OVF_CAP * 4;
        off = (off + 15) & ~(size_t)15;
        size_t ovfcv_off = off;               off += (size_t)OVF_CAP * 8;
        size_t rptr_off  = off;               off += (size_t)nrp * 4;
        off = (off + 15) & ~(size_t)15;
        size_t binbuf_off = off;              off += (size_t)nbins * SEG_CAP * 8;
        off = (off + 15) & ~(size_t)15;
        size_t xh_off    = off;               off += (size_t)N * D * 2;
        size_t need = off;

        if (D == 256 && N <= (1 << 17) && nbins <= MAXBINS && ws_size >= need) {
            int* bin_cnt = (int*)((char*)d_ws + cnt_off);
            int* ovf_cnt = (int*)((char*)d_ws + ovfc_off);
            int* ovf_r   = (int*)((char*)d_ws + ovfr_off);
            u64* ovf_cv  = (u64*)((char*)d_ws + ovfcv_off);
            int* row_ptr = (int*)((char*)d_ws + rptr_off);
            u64* binbuf  = (u64*)((char*)d_ws + binbuf_off);
            unsigned short* xh = (unsigned short*)((char*)d_ws + xh_off);

            (void)hipMemsetAsync(bin_cnt, 0, (size_t)nbins * 4 + 16, stream);
            int n8 = (N * D) / 8;
            convert_bf16_256_kernel<<<2048, 256, 0, stream>>>(
                (const u32x4*)x, (u32x4*)xh, out_norm, n8);
            int ntiles = (E + TILE - 1) / TILE;
            binfill_ms_kernel<<<ntiles, 256, 0, stream>>>(
                row, col, values, bin_cnt, binbuf, ovf_cnt, ovf_r, ovf_cv,
                E, nbins);
            sort_bins_kernel<<<nbins, 256, 0, stream>>>(
                binbuf, bin_cnt, row_ptr, nbins);
            gather_csr_kernel<<<(N + 3) / 4, 256, 0, stream>>>(
                xh, binbuf, row_ptr, in_norm, out, N);
            fixup_kernel<<<8, 256, 0, stream>>>(
                xh, ovf_cnt, ovf_r, ovf_cv, in_norm, out);
            return;
        }
    }

    // ---------- R10 bucket fallback (D==256) ----------
    {
        size_t off = 0;
        size_t cursor_off = off;              off += (size_t)N * 4;
        size_t ovfc_off   = off;              off += 16;
        size_t ovfr_off   = off;              off += (size_t)OVF_CAP * 4;
        off = (off + 15) & ~(size_t)15;
        size_t ovfcv_off  = off;              off += (size_t)OVF_CAP * 8;
        off = (off + 15) & ~(size_t)15;
        size_t pairs_off  = off;              off += ((size_t)N << BUCKET_LOG2) * 4;
        off = (off + 15) & ~(size_t)15;
        size_t xh_off     = off;              off += (size_t)N * D * 2;
        size_t need_bucket = off;

        if (D == 256 && N <= (1 << 17) && ws_size >= need_bucket) {
            int*      cursor  = (int*)((char*)d_ws + cursor_off);
            int*      ovf_cnt = (int*)((char*)d_ws + ovfc_off);
            int*      ovf_r   = (int*)((char*)d_ws + ovfr_off);
            u64*      ovf_cv  = (u64*)((char*)d_ws + ovfcv_off);
            unsigned* pairs   = (unsigned*)((char*)d_ws + pairs_off);
            unsigned short* xh = (unsigned short*)((char*)d_ws + xh_off);

            (void)hipMemsetAsync(cursor, 0, (size_t)N * 4 + 16, stream);
            int n8 = (N * D) / 8;
            convert_bf16_256_kernel<<<2048, 256, 0, stream>>>(
                (const u32x4*)x, (u32x4*)xh, out_norm, n8);
            fill_bucket4_kernel<<<2048, 256, 0, stream>>>(
                row, col, values, cursor, pairs, ovf_cnt, ovf_r, ovf_cv, E);
            gather_bucket4_kernel<<<(N + 3) / 4, 256, 0, stream>>>(
                xh, pairs, cursor, in_norm, out, N);
            fixup_kernel<<<8, 256, 0, stream>>>(
                xh, ovf_cnt, ovf_r, ovf_cv, in_norm, out);
            return;
        }
    }

    // ---------- last resort: atomic scatter ----------
    int n4 = (N * D) / 4;
    zero_out_kernel<<<2048, 256, 0, stream>>>((float4*)out, n4);
    int blocks = (E + 3) / 4;
    edge_scatter_kernel<<<blocks, 256, 0, stream>>>(
        x, row, col, values, out_norm, in_norm, out, E, D);
}